// Round 2
// baseline (3140.066 us; speedup 1.0000x reference)
//
#include <hip/hip_runtime.h>
#include <hip/hip_bf16.h>
#include <math.h>

// Problem dims (fixed by reference)
#define NTOK 98304      // 32768 * 3
#define DIN  256
#define DE   512
#define DH   512
#define DC   64
#define NCODE 1024
#define CHUNK 16384     // tokens per pipeline chunk (6 chunks)

__device__ __forceinline__ float gelu_f(float x) {
    // jax.nn.gelu approximate=True (tanh form)
    const float k0 = 0.7978845608028654f;  // sqrt(2/pi)
    const float k1 = 0.044715f;
    float x3 = x * x * x;
    return 0.5f * x * (1.0f + tanhf(k0 * (x + k1 * x3)));
}

// C[M,N] = gelu(A[M,K] @ W[K,N] + bias[N]), fp32, 256 threads/block
template<int BM, int BN, int TM, int TN>
__global__ __launch_bounds__(256, 2)
void gemm_bias_gelu(const float* __restrict__ A, const float* __restrict__ W,
                    const float* __restrict__ bias, float* __restrict__ C,
                    int M, int N, int K)
{
    constexpr int BK = 16;
    __shared__ float As[BK][BM + 4];   // +4 pad keeps float4 alignment, spreads banks
    __shared__ float Bs[BK][BN];
    const int tid  = threadIdx.x;
    const int tcol = tid % (BN / TN);
    const int trow = tid / (BN / TN);
    const int m0 = blockIdx.y * BM;
    const int n0 = blockIdx.x * BN;

    float acc[TM][TN];
#pragma unroll
    for (int i = 0; i < TM; ++i)
#pragma unroll
        for (int j = 0; j < TN; ++j) acc[i][j] = 0.f;

    for (int k0 = 0; k0 < K; k0 += BK) {
        // A tile: BM x 16, stored transposed As[k][m]
#pragma unroll
        for (int r = 0; r < BM / 64; ++r) {
            int row = (tid >> 2) + r * 64;
            int c0  = (tid & 3) * 4;
            float4 v = *(const float4*)(A + (size_t)(m0 + row) * K + k0 + c0);
            As[c0 + 0][row] = v.x;
            As[c0 + 1][row] = v.y;
            As[c0 + 2][row] = v.z;
            As[c0 + 3][row] = v.w;
        }
        // B tile: 16 x BN, Bs[k][n]
#pragma unroll
        for (int r = 0; r < BN / 64; ++r) {
            int idx = tid + r * 256;
            int kr  = idx / (BN / 4);
            int nc  = (idx % (BN / 4)) * 4;
            *(float4*)(&Bs[kr][nc]) = *(const float4*)(W + (size_t)(k0 + kr) * N + n0 + nc);
        }
        __syncthreads();
#pragma unroll
        for (int kk = 0; kk < BK; ++kk) {
            float a[TM], b[TN];
#pragma unroll
            for (int i = 0; i < TM; i += 4) {
                float4 v = *(const float4*)(&As[kk][trow * TM + i]);
                a[i] = v.x; a[i + 1] = v.y; a[i + 2] = v.z; a[i + 3] = v.w;
            }
#pragma unroll
            for (int j = 0; j < TN; j += 4) {
                float4 v = *(const float4*)(&Bs[kk][tcol * TN + j]);
                b[j] = v.x; b[j + 1] = v.y; b[j + 2] = v.z; b[j + 3] = v.w;
            }
#pragma unroll
            for (int i = 0; i < TM; ++i)
#pragma unroll
                for (int j = 0; j < TN; ++j)
                    acc[i][j] = fmaf(a[i], b[j], acc[i][j]);
        }
        __syncthreads();
    }

    float bv[TN];
#pragma unroll
    for (int j = 0; j < TN; ++j) bv[j] = bias[n0 + tcol * TN + j];
#pragma unroll
    for (int i = 0; i < TM; ++i) {
        int row = m0 + trow * TM + i;
        float outv[TN];
#pragma unroll
        for (int j = 0; j < TN; ++j) outv[j] = gelu_f(acc[i][j] + bv[j]);
#pragma unroll
        for (int j = 0; j < TN; j += 4) {
            float4 v; v.x = outv[j]; v.y = outv[j + 1]; v.z = outv[j + 2]; v.w = outv[j + 3];
            *(float4*)(C + (size_t)row * N + n0 + tcol * TN + j) = v;
        }
    }
}

// VQ: per 64-token block — argmin over 1024 codes, gather quantized,
// loss partial, counts histogram, dw scatter.
__global__ __launch_bounds__(256, 2)
void vq_kernel(const float* __restrict__ latent, const float* __restrict__ emb,
               float* __restrict__ quant_out, float* __restrict__ encidx_out,
               float* __restrict__ dw, unsigned int* __restrict__ counts,
               float* __restrict__ sum_sq)
{
    __shared__ float latT[DC][68];      // [c][token], pad 68 -> aligned & 2-way banks
    __shared__ float Ec[DC][128];       // code chunk [c][j]
    __shared__ float e2all[NCODE];
    __shared__ float red_d[64][17];
    __shared__ int   red_i[64][17];
    __shared__ int   sidx[64];
    __shared__ float wred[4];

    const int tid  = threadIdx.x;
    const int tok0 = blockIdx.x * 64;

    // |e_k|^2 for all codes (coalesced along k; emb is L2-resident)
#pragma unroll
    for (int r = 0; r < 4; ++r) {
        int k = tid + r * 256;
        float s = 0.f;
#pragma unroll
        for (int c = 0; c < DC; ++c) { float e = emb[(size_t)c * NCODE + k]; s = fmaf(e, e, s); }
        e2all[k] = s;
    }
    // latent tile -> transposed LDS
#pragma unroll
    for (int r = 0; r < 4; ++r) {
        int t  = (tid >> 4) + r * 16;
        int c0 = (tid & 15) * 4;
        float4 v = *(const float4*)(latent + (size_t)(tok0 + t) * DC + c0);
        latT[c0 + 0][t] = v.x; latT[c0 + 1][t] = v.y;
        latT[c0 + 2][t] = v.z; latT[c0 + 3][t] = v.w;
    }

    const int tx = tid & 15;   // code groups: {tx*4..+3} and {64+tx*4..+3} per chunk
    const int ty = tid >> 4;   // tokens ty*4..+3
    float bd[4]; int bi[4];
#pragma unroll
    for (int t = 0; t < 4; ++t) { bd[t] = INFINITY; bi[t] = 0; }

    for (int k0 = 0; k0 < NCODE; k0 += 128) {
        __syncthreads();   // also covers latT/e2all on first iteration
#pragma unroll
        for (int r = 0; r < 8; ++r) {
            int c = (tid >> 5) + r * 8;
            int f = (tid & 31) * 4;
            *(float4*)(&Ec[c][f]) = *(const float4*)(emb + (size_t)c * NCODE + k0 + f);
        }
        __syncthreads();

        float acc[4][8];
#pragma unroll
        for (int t = 0; t < 4; ++t)
#pragma unroll
            for (int j = 0; j < 8; ++j) acc[t][j] = 0.f;

        for (int c = 0; c < DC; ++c) {
            float4 av = *(const float4*)(&latT[c][ty * 4]);
            float4 b0 = *(const float4*)(&Ec[c][tx * 4]);
            float4 b1 = *(const float4*)(&Ec[c][64 + tx * 4]);
            float a[4]  = {av.x, av.y, av.z, av.w};
            float bb[8] = {b0.x, b0.y, b0.z, b0.w, b1.x, b1.y, b1.z, b1.w};
#pragma unroll
            for (int t = 0; t < 4; ++t)
#pragma unroll
                for (int j = 0; j < 8; ++j)
                    acc[t][j] = fmaf(a[t], bb[j], acc[t][j]);
        }
        // d = |e|^2 - 2 x.e  (|x|^2 constant per row, argmin-invariant)
#pragma unroll
        for (int t = 0; t < 4; ++t) {
#pragma unroll
            for (int j = 0; j < 8; ++j) {
                int k = k0 + ((j < 4) ? (tx * 4 + j) : (64 + tx * 4 + (j - 4)));
                float d = e2all[k] - 2.f * acc[t][j];
                if (d < bd[t]) { bd[t] = d; bi[t] = k; }  // strict < => first occurrence
            }
        }
    }

#pragma unroll
    for (int t = 0; t < 4; ++t) {
        red_d[ty * 4 + t][tx] = bd[t];
        red_i[ty * 4 + t][tx] = bi[t];
    }
    __syncthreads();
    if (tid < 64) {
        float d0 = red_d[tid][0]; int i0 = red_i[tid][0];
        for (int x = 1; x < 16; ++x) {
            float d = red_d[tid][x]; int i = red_i[tid][x];
            if (d < d0 || (d == d0 && i < i0)) { d0 = d; i0 = i; }
        }
        sidx[tid] = i0;
        encidx_out[tok0 + tid] = (float)i0;
        atomicAdd(&counts[i0], 1u);
    }
    __syncthreads();

    // phase 2: gather quantized, loss, dw scatter
    const int t2 = tid >> 2;
    const int g  = tid & 3;
    const int code = sidx[t2];
    float lsum = 0.f;
#pragma unroll
    for (int q = 0; q < 4; ++q) {
        int c0 = g * 16 + q * 4;
        float qv[4];
#pragma unroll
        for (int j = 0; j < 4; ++j) {
            float lv = latT[c0 + j][t2];
            qv[j] = emb[(size_t)(c0 + j) * NCODE + code];
            atomicAdd(&dw[(size_t)(c0 + j) * NCODE + code], lv);
            float df = qv[j] - lv;
            lsum = fmaf(df, df, lsum);
        }
        float4 v; v.x = qv[0]; v.y = qv[1]; v.z = qv[2]; v.w = qv[3];
        *(float4*)(quant_out + (size_t)(tok0 + t2) * DC + c0) = v;
    }
#pragma unroll
    for (int o = 32; o > 0; o >>= 1) lsum += __shfl_down(lsum, o);
    if ((tid & 63) == 0) wred[tid >> 6] = lsum;
    __syncthreads();
    if (tid == 0) atomicAdd(sum_sq, wred[0] + wred[1] + wred[2] + wred[3]);
}

__global__ __launch_bounds__(1024)
void finalize_kernel(const unsigned int* __restrict__ counts,
                     const float* __restrict__ dw,
                     const float* __restrict__ ema_ch,
                     const float* __restrict__ ema_dw,
                     const float* __restrict__ sum_sq,
                     float* __restrict__ out_loss, float* __restrict__ out_perp,
                     float* __restrict__ out_newemb)
{
    __shared__ float sred[1024];
    const int k = threadIdx.x;
    const float debias = (float)(1.0 - pow(0.99, 1001.0));  // zero-debias
    float cnt = (float)counts[k];
    float cs  = (ema_ch[k] * 0.99f + cnt * 0.01f) / debias;

    sred[k] = cs; __syncthreads();
    for (int s = 512; s > 0; s >>= 1) { if (k < s) sred[k] += sred[k + s]; __syncthreads(); }
    float n = sred[0];
    __syncthreads();

    float p = cnt / 98304.0f;
    sred[k] = p * logf(p + 1e-10f);
    __syncthreads();
    for (int s = 512; s > 0; s >>= 1) { if (k < s) sred[k] += sred[k + s]; __syncthreads(); }
    if (k == 0) {
        out_perp[0] = expf(-sred[0]);
        out_loss[0] = 0.25f * sum_sq[0] / 6291456.0f;
    }

    float stable = (cs + 1e-5f) / (n + 1024.0f * 1e-5f) * n;
#pragma unroll
    for (int c = 0; c < 64; ++c) {
        size_t o = (size_t)c * 1024 + k;
        out_newemb[o] = ((ema_dw[o] * 0.99f + dw[o] * 0.01f) / debias) / stable;
    }
}

extern "C" void kernel_launch(void* const* d_in, const int* in_sizes, int n_in,
                              void* d_out, int out_size, void* d_ws, size_t ws_size,
                              hipStream_t stream)
{
    (void)in_sizes; (void)n_in; (void)out_size; (void)ws_size;
    const float* states = (const float*)d_in[0];
    const float* w_se   = (const float*)d_in[1];
    const float* b_se   = (const float*)d_in[2];
    const float* w0     = (const float*)d_in[3];
    const float* b0     = (const float*)d_in[4];
    const float* w1     = (const float*)d_in[5];
    const float* b1     = (const float*)d_in[6];
    const float* w2     = (const float*)d_in[7];
    const float* b2     = (const float*)d_in[8];
    const float* emb    = (const float*)d_in[9];
    const float* ema_ch = (const float*)d_in[10];
    const float* ema_dw = (const float*)d_in[11];

    float* out        = (float*)d_out;
    float* q_out      = out;                    // 6291456
    float* loss_out   = out + 6291456;          // 1
    float* perp_out   = out + 6291457;          // 1
    float* idx_out    = out + 6291458;          // 98304 (float-encoded ints)
    float* newemb_out = out + 6389762;          // 65536

    // workspace: small VQ scratch + chunk-sized activation ping-pong (~68 MB total)
    char* ws = (char*)d_ws;
    float*        dwb    = (float*)ws;                        // 262144 B
    unsigned int* counts = (unsigned int*)(ws + 262144);      // 4096 B
    float*        sumsq  = (float*)(ws + 266240);             // 4 B (pad to 266496)
    float* bufA = (float*)(ws + 266496);                      // CHUNK*512 f = 33.5 MB
    float* bufB = (float*)(ws + 266496 + (size_t)CHUNK * 512 * 4);
    float* lat  = (float*)(ws + 266496 + 2ull * CHUNK * 512 * 4);  // CHUNK*64 f

    hipMemsetAsync(d_ws, 0, 266244, stream);

    dim3 blk(256);
    const int MB = CHUNK / 128;   // 128 M-blocks per chunk
    for (int c = 0; c < NTOK / CHUNK; ++c) {
        size_t off = (size_t)c * CHUNK;
        gemm_bias_gelu<128,128,8,8><<<dim3(4, MB), blk, 0, stream>>>(
            states + off * DIN, w_se, b_se, bufA, CHUNK, DE, DIN);
        gemm_bias_gelu<128,128,8,8><<<dim3(4, MB), blk, 0, stream>>>(
            bufA, w0, b0, bufB, CHUNK, DH, DE);
        gemm_bias_gelu<128,128,8,8><<<dim3(4, MB), blk, 0, stream>>>(
            bufB, w1, b1, bufA, CHUNK, DH, DH);
        gemm_bias_gelu<128,64,8,4><<<dim3(1, MB), blk, 0, stream>>>(
            bufA, w2, b2, lat, CHUNK, DC, DH);
        vq_kernel<<<dim3(CHUNK / 64), blk, 0, stream>>>(
            lat, emb, q_out + off * DC, idx_out + off, dwb, counts, sumsq);
    }
    finalize_kernel<<<dim3(1), dim3(1024), 0, stream>>>(counts, dwb, ema_ch, ema_dw, sumsq,
                                                        loss_out, perp_out, newemb_out);
}

// Round 3
// 1490.101 us; speedup vs baseline: 2.1073x; 2.1073x over previous
//
#include <hip/hip_runtime.h>
#include <hip/hip_bf16.h>
#include <math.h>

// Problem dims (fixed by reference)
#define NTOK 98304      // 32768 * 3
#define DIN  256
#define DE   512
#define DH   512
#define DC   64
#define NCODE 1024
#define CHUNK 16384     // tokens per pipeline chunk (6 chunks)

typedef _Float16 half8 __attribute__((ext_vector_type(8)));
typedef float f32x4 __attribute__((ext_vector_type(4)));

__device__ __forceinline__ float gelu_f(float x) {
    // jax.nn.gelu approximate=True (tanh form)
    const float k0 = 0.7978845608028654f;  // sqrt(2/pi)
    const float k1 = 0.044715f;
    float x3 = x * x * x;
    return 0.5f * x * (1.0f + tanhf(k0 * (x + k1 * x3)));
}

// split fp32 -> (hi fp16, lo fp16) packed in uint32 (lo in high 16 bits)
__device__ __forceinline__ unsigned int split_pack(float x) {
    _Float16 hi = (_Float16)x;
    float hif = (float)hi;
    _Float16 lo = (_Float16)(x - hif);
    unsigned short uh = __builtin_bit_cast(unsigned short, hi);
    unsigned short ul = __builtin_bit_cast(unsigned short, lo);
    return (unsigned int)uh | ((unsigned int)ul << 16);
}

// W[K][N] fp32 -> Wt[N][K] packed half2(hi,lo)
__global__ __launch_bounds__(256)
void transpose_split(const float* __restrict__ W, unsigned int* __restrict__ Wt,
                     int K, int N)
{
    int e = blockIdx.x * 256 + threadIdx.x;
    if (e >= K * N) return;
    int k = e / N, n = e % N;
    Wt[(size_t)n * K + k] = split_pack(W[e]);
}

// C = gelu(A @ W + b) with fp16x3 MFMA (Ah*Bh + Ah*Bl + Al*Bh), fp32 accum.
// A: A_F32 ? fp32 [M][K] : packed half2 [M][K].  Wt: packed half2 [N][K] (B^T).
// Out: EMIT_F32 ? fp32 [M][N] : packed half2 [M][N].
template<int BN, bool A_F32, bool EMIT_F32>
__global__ __launch_bounds__(256, 2)
void gemm_f16x3(const void* __restrict__ Aptr, const unsigned int* __restrict__ Wt,
                const float* __restrict__ bias, void* __restrict__ Cptr,
                int M, int N, int K)
{
    constexpr int BM = 128, BK = 32;
    constexpr int WGM = (BN == 128) ? 2 : 4;   // wave grid in m
    constexpr int WAVE_M = BM / WGM;           // 64 or 32
    constexpr int MT = WAVE_M / 16;            // 4 or 2
    constexpr int NT = 4;                      // wave covers 64 cols always

    __shared__ _Float16 Ah[BM][40], Al[BM][40];   // rows padded 32->40 (bank spread)
    __shared__ _Float16 Bh[BN][40], Bl[BN][40];

    const int tid  = threadIdx.x;
    const int lane = tid & 63, wid = tid >> 6;
    const int lm   = lane & 15, quad = lane >> 4;
    const int wave_m = (BN == 128) ? (wid & 1) * 64 : wid * 32;
    const int wave_n = (BN == 128) ? (wid >> 1) * 64 : 0;
    const int m0 = blockIdx.y * BM, n0 = blockIdx.x * BN;

    f32x4 acc[MT][NT];
#pragma unroll
    for (int mi = 0; mi < MT; ++mi)
#pragma unroll
        for (int ni = 0; ni < NT; ++ni) acc[mi][ni] = (f32x4)(0.f);

    for (int k0 = 0; k0 < K; k0 += BK) {
        // ---- stage A tile: BM x 32, 4 elems per load-slot ----
#pragma unroll
        for (int i = 0; i < (BM * (BK / 4)) / 256; ++i) {
            int s = tid + i * 256;
            int row = s >> 3, kc = (s & 7) * 4;
            unsigned short h[4], l[4];
            if (A_F32) {
                const float* A = (const float*)Aptr;
                float4 v = *(const float4*)(A + (size_t)(m0 + row) * K + k0 + kc);
                float vv[4] = {v.x, v.y, v.z, v.w};
#pragma unroll
                for (int j = 0; j < 4; ++j) {
                    unsigned int p = split_pack(vv[j]);
                    h[j] = p & 0xffff; l[j] = p >> 16;
                }
            } else {
                const unsigned int* A = (const unsigned int*)Aptr;
                uint4 v = *(const uint4*)(A + (size_t)(m0 + row) * K + k0 + kc);
                unsigned int vv[4] = {v.x, v.y, v.z, v.w};
#pragma unroll
                for (int j = 0; j < 4; ++j) { h[j] = vv[j] & 0xffff; l[j] = vv[j] >> 16; }
            }
            uint2 ph, pl;
            ph.x = (unsigned int)h[0] | ((unsigned int)h[1] << 16);
            ph.y = (unsigned int)h[2] | ((unsigned int)h[3] << 16);
            pl.x = (unsigned int)l[0] | ((unsigned int)l[1] << 16);
            pl.y = (unsigned int)l[2] | ((unsigned int)l[3] << 16);
            *(uint2*)&Ah[row][kc] = ph;
            *(uint2*)&Al[row][kc] = pl;
        }
        // ---- stage B tile: BN x 32 from Wt[N][K] ----
#pragma unroll
        for (int i = 0; i < (BN * (BK / 4)) / 256; ++i) {
            int s = tid + i * 256;
            int row = s >> 3, kc = (s & 7) * 4;
            uint4 v = *(const uint4*)(Wt + (size_t)(n0 + row) * K + k0 + kc);
            unsigned int vv[4] = {v.x, v.y, v.z, v.w};
            unsigned short h[4], l[4];
#pragma unroll
            for (int j = 0; j < 4; ++j) { h[j] = vv[j] & 0xffff; l[j] = vv[j] >> 16; }
            uint2 ph, pl;
            ph.x = (unsigned int)h[0] | ((unsigned int)h[1] << 16);
            ph.y = (unsigned int)h[2] | ((unsigned int)h[3] << 16);
            pl.x = (unsigned int)l[0] | ((unsigned int)l[1] << 16);
            pl.y = (unsigned int)l[2] | ((unsigned int)l[3] << 16);
            *(uint2*)&Bh[row][kc] = ph;
            *(uint2*)&Bl[row][kc] = pl;
        }
        __syncthreads();

        // ---- fragments + 3-term MFMA (one K=32 step per tile) ----
        half8 ahf[MT], alf[MT], bhf[NT], blf[NT];
#pragma unroll
        for (int mi = 0; mi < MT; ++mi) {
            int r = wave_m + mi * 16 + lm;
            ahf[mi] = *(const half8*)&Ah[r][quad * 8];
            alf[mi] = *(const half8*)&Al[r][quad * 8];
        }
#pragma unroll
        for (int ni = 0; ni < NT; ++ni) {
            int r = wave_n + ni * 16 + lm;
            bhf[ni] = *(const half8*)&Bh[r][quad * 8];
            blf[ni] = *(const half8*)&Bl[r][quad * 8];
        }
#pragma unroll
        for (int mi = 0; mi < MT; ++mi)
#pragma unroll
            for (int ni = 0; ni < NT; ++ni) {
                acc[mi][ni] = __builtin_amdgcn_mfma_f32_16x16x32_f16(ahf[mi], bhf[ni], acc[mi][ni], 0, 0, 0);
                acc[mi][ni] = __builtin_amdgcn_mfma_f32_16x16x32_f16(ahf[mi], blf[ni], acc[mi][ni], 0, 0, 0);
                acc[mi][ni] = __builtin_amdgcn_mfma_f32_16x16x32_f16(alf[mi], bhf[ni], acc[mi][ni], 0, 0, 0);
            }
        __syncthreads();
    }

    // ---- epilogue: bias + gelu, emit packed half2 or fp32 ----
#pragma unroll
    for (int ni = 0; ni < NT; ++ni) {
        int col = n0 + wave_n + ni * 16 + lm;
        float bv = bias[col];
#pragma unroll
        for (int mi = 0; mi < MT; ++mi) {
            int rowbase = m0 + wave_m + mi * 16 + quad * 4;
#pragma unroll
            for (int r = 0; r < 4; ++r) {
                float g = gelu_f(acc[mi][ni][r] + bv);
                if (EMIT_F32) {
                    ((float*)Cptr)[(size_t)(rowbase + r) * N + col] = g;
                } else {
                    ((unsigned int*)Cptr)[(size_t)(rowbase + r) * N + col] = split_pack(g);
                }
            }
        }
    }
}

// VQ: per 64-token block — argmin over 1024 codes, gather quantized,
// loss partial, counts histogram, dw scatter. (fp32 exact distance path)
__global__ __launch_bounds__(256, 2)
void vq_kernel(const float* __restrict__ latent, const float* __restrict__ emb,
               float* __restrict__ quant_out, float* __restrict__ encidx_out,
               float* __restrict__ dw, unsigned int* __restrict__ counts,
               float* __restrict__ sum_sq)
{
    __shared__ float latT[DC][68];
    __shared__ float Ec[DC][128];
    __shared__ float e2all[NCODE];
    __shared__ float red_d[64][17];
    __shared__ int   red_i[64][17];
    __shared__ int   sidx[64];
    __shared__ float wred[4];

    const int tid  = threadIdx.x;
    const int tok0 = blockIdx.x * 64;

#pragma unroll
    for (int r = 0; r < 4; ++r) {
        int k = tid + r * 256;
        float s = 0.f;
#pragma unroll
        for (int c = 0; c < DC; ++c) { float e = emb[(size_t)c * NCODE + k]; s = fmaf(e, e, s); }
        e2all[k] = s;
    }
#pragma unroll
    for (int r = 0; r < 4; ++r) {
        int t  = (tid >> 4) + r * 16;
        int c0 = (tid & 15) * 4;
        float4 v = *(const float4*)(latent + (size_t)(tok0 + t) * DC + c0);
        latT[c0 + 0][t] = v.x; latT[c0 + 1][t] = v.y;
        latT[c0 + 2][t] = v.z; latT[c0 + 3][t] = v.w;
    }

    const int tx = tid & 15;
    const int ty = tid >> 4;
    float bd[4]; int bi[4];
#pragma unroll
    for (int t = 0; t < 4; ++t) { bd[t] = INFINITY; bi[t] = 0; }

    for (int k0 = 0; k0 < NCODE; k0 += 128) {
        __syncthreads();
#pragma unroll
        for (int r = 0; r < 8; ++r) {
            int c = (tid >> 5) + r * 8;
            int f = (tid & 31) * 4;
            *(float4*)(&Ec[c][f]) = *(const float4*)(emb + (size_t)c * NCODE + k0 + f);
        }
        __syncthreads();

        float acc[4][8];
#pragma unroll
        for (int t = 0; t < 4; ++t)
#pragma unroll
            for (int j = 0; j < 8; ++j) acc[t][j] = 0.f;

        for (int c = 0; c < DC; ++c) {
            float4 av = *(const float4*)(&latT[c][ty * 4]);
            float4 b0 = *(const float4*)(&Ec[c][tx * 4]);
            float4 b1 = *(const float4*)(&Ec[c][64 + tx * 4]);
            float a[4]  = {av.x, av.y, av.z, av.w};
            float bb[8] = {b0.x, b0.y, b0.z, b0.w, b1.x, b1.y, b1.z, b1.w};
#pragma unroll
            for (int t = 0; t < 4; ++t)
#pragma unroll
                for (int j = 0; j < 8; ++j)
                    acc[t][j] = fmaf(a[t], bb[j], acc[t][j]);
        }
#pragma unroll
        for (int t = 0; t < 4; ++t) {
#pragma unroll
            for (int j = 0; j < 8; ++j) {
                int k = k0 + ((j < 4) ? (tx * 4 + j) : (64 + tx * 4 + (j - 4)));
                float d = e2all[k] - 2.f * acc[t][j];
                if (d < bd[t]) { bd[t] = d; bi[t] = k; }
            }
        }
    }

#pragma unroll
    for (int t = 0; t < 4; ++t) {
        red_d[ty * 4 + t][tx] = bd[t];
        red_i[ty * 4 + t][tx] = bi[t];
    }
    __syncthreads();
    if (tid < 64) {
        float d0 = red_d[tid][0]; int i0 = red_i[tid][0];
        for (int x = 1; x < 16; ++x) {
            float d = red_d[tid][x]; int i = red_i[tid][x];
            if (d < d0 || (d == d0 && i < i0)) { d0 = d; i0 = i; }
        }
        sidx[tid] = i0;
        encidx_out[tok0 + tid] = (float)i0;
        atomicAdd(&counts[i0], 1u);
    }
    __syncthreads();

    const int t2 = tid >> 2;
    const int g  = tid & 3;
    const int code = sidx[t2];
    float lsum = 0.f;
#pragma unroll
    for (int q = 0; q < 4; ++q) {
        int c0 = g * 16 + q * 4;
        float qv[4];
#pragma unroll
        for (int j = 0; j < 4; ++j) {
            float lv = latT[c0 + j][t2];
            qv[j] = emb[(size_t)(c0 + j) * NCODE + code];
            atomicAdd(&dw[(size_t)(c0 + j) * NCODE + code], lv);
            float df = qv[j] - lv;
            lsum = fmaf(df, df, lsum);
        }
        float4 v; v.x = qv[0]; v.y = qv[1]; v.z = qv[2]; v.w = qv[3];
        *(float4*)(quant_out + (size_t)(tok0 + t2) * DC + c0) = v;
    }
#pragma unroll
    for (int o = 32; o > 0; o >>= 1) lsum += __shfl_down(lsum, o);
    if ((tid & 63) == 0) wred[tid >> 6] = lsum;
    __syncthreads();
    if (tid == 0) atomicAdd(sum_sq, wred[0] + wred[1] + wred[2] + wred[3]);
}

__global__ __launch_bounds__(1024)
void finalize_kernel(const unsigned int* __restrict__ counts,
                     const float* __restrict__ dw,
                     const float* __restrict__ ema_ch,
                     const float* __restrict__ ema_dw,
                     const float* __restrict__ sum_sq,
                     float* __restrict__ out_loss, float* __restrict__ out_perp,
                     float* __restrict__ out_newemb)
{
    __shared__ float sred[1024];
    const int k = threadIdx.x;
    const float debias = (float)(1.0 - pow(0.99, 1001.0));
    float cnt = (float)counts[k];
    float cs  = (ema_ch[k] * 0.99f + cnt * 0.01f) / debias;

    sred[k] = cs; __syncthreads();
    for (int s = 512; s > 0; s >>= 1) { if (k < s) sred[k] += sred[k + s]; __syncthreads(); }
    float n = sred[0];
    __syncthreads();

    float p = cnt / 98304.0f;
    sred[k] = p * logf(p + 1e-10f);
    __syncthreads();
    for (int s = 512; s > 0; s >>= 1) { if (k < s) sred[k] += sred[k + s]; __syncthreads(); }
    if (k == 0) {
        out_perp[0] = expf(-sred[0]);
        out_loss[0] = 0.25f * sum_sq[0] / 6291456.0f;
    }

    float stable = (cs + 1e-5f) / (n + 1024.0f * 1e-5f) * n;
#pragma unroll
    for (int c = 0; c < 64; ++c) {
        size_t o = (size_t)c * 1024 + k;
        out_newemb[o] = ((ema_dw[o] * 0.99f + dw[o] * 0.01f) / debias) / stable;
    }
}

extern "C" void kernel_launch(void* const* d_in, const int* in_sizes, int n_in,
                              void* d_out, int out_size, void* d_ws, size_t ws_size,
                              hipStream_t stream)
{
    (void)in_sizes; (void)n_in; (void)out_size; (void)ws_size;
    const float* states = (const float*)d_in[0];
    const float* w_se   = (const float*)d_in[1];
    const float* b_se   = (const float*)d_in[2];
    const float* w0     = (const float*)d_in[3];
    const float* b0     = (const float*)d_in[4];
    const float* w1     = (const float*)d_in[5];
    const float* b1     = (const float*)d_in[6];
    const float* w2     = (const float*)d_in[7];
    const float* b2     = (const float*)d_in[8];
    const float* emb    = (const float*)d_in[9];
    const float* ema_ch = (const float*)d_in[10];
    const float* ema_dw = (const float*)d_in[11];

    float* out        = (float*)d_out;
    float* q_out      = out;                    // 6291456
    float* loss_out   = out + 6291456;          // 1
    float* perp_out   = out + 6291457;          // 1
    float* idx_out    = out + 6291458;          // 98304 (float-encoded ints)
    float* newemb_out = out + 6389762;          // 65536

    // workspace layout (~91 MB)
    char* ws = (char*)d_ws;
    float*        dwb    = (float*)ws;                         // 262144 B
    unsigned int* counts = (unsigned int*)(ws + 262144);       // 4096 B
    float*        sumsq  = (float*)(ws + 266240);              // 4 B
    unsigned int* wse_t  = (unsigned int*)(ws + 266496);       // 256*512*4  = 524288
    unsigned int* w0t    = (unsigned int*)(ws + 790784);       // 512*512*4  = 1048576
    unsigned int* w1t    = (unsigned int*)(ws + 1839360);      // 1048576
    unsigned int* w2t    = (unsigned int*)(ws + 2887936);      // 512*64*4   = 131072
    unsigned int* bufA   = (unsigned int*)(ws + 3019008);      // CHUNK*512*4 = 33554432
    unsigned int* bufB   = (unsigned int*)(ws + 36573440);     // 33554432
    float*        lat    = (float*)(ws + 70127872);            // NTOK*64*4 = 25165824

    hipMemsetAsync(d_ws, 0, 266244, stream);

    // weight prep: transpose + fp16 hi/lo split (per-launch, tiny)
    transpose_split<<<dim3((DIN * DE + 255) / 256), dim3(256), 0, stream>>>(w_se, wse_t, DIN, DE);
    transpose_split<<<dim3((DE * DH + 255) / 256), dim3(256), 0, stream>>>(w0, w0t, DE, DH);
    transpose_split<<<dim3((DH * DH + 255) / 256), dim3(256), 0, stream>>>(w1, w1t, DH, DH);
    transpose_split<<<dim3((DH * DC + 255) / 256), dim3(256), 0, stream>>>(w2, w2t, DH, DC);

    dim3 blk(256);
    const int MBLK = CHUNK / 128;
    for (int c = 0; c < NTOK / CHUNK; ++c) {
        size_t off = (size_t)c * CHUNK;
        gemm_f16x3<128, true,  false><<<dim3(DE / 128, MBLK), blk, 0, stream>>>(
            states + off * DIN, wse_t, b_se, bufA, CHUNK, DE, DIN);
        gemm_f16x3<128, false, false><<<dim3(DH / 128, MBLK), blk, 0, stream>>>(
            bufA, w0t, b0, bufB, CHUNK, DH, DE);
        gemm_f16x3<128, false, false><<<dim3(DH / 128, MBLK), blk, 0, stream>>>(
            bufB, w1t, b1, bufA, CHUNK, DH, DH);
        gemm_f16x3<64,  false, true ><<<dim3(1, MBLK), blk, 0, stream>>>(
            bufA, w2t, b2, lat + off * DC, CHUNK, DC, DH);
    }
    vq_kernel<<<dim3(NTOK / 64), blk, 0, stream>>>(lat, emb, q_out, idx_out, dwb, counts, sumsq);
    finalize_kernel<<<dim3(1), dim3(1024), 0, stream>>>(counts, dwb, ema_ch, ema_dw, sumsq,
                                                        loss_out, perp_out, newemb_out);
}